// Round 9
// baseline (213.727 us; speedup 1.0000x reference)
//
#include <hip/hip_runtime.h>

#define S_LEN 2048

typedef float f32x4 __attribute__((ext_vector_type(4)));

__device__ __forceinline__ float rlane(float v, int l) {
    return __int_as_float(__builtin_amdgcn_readlane(__float_as_int(v), l));
}

template<int CTRL, int RM>
__device__ __forceinline__ float dpp_add(float v) {
    int t = __builtin_amdgcn_update_dpp(0, __float_as_int(v), CTRL, RM, 0xF, true);
    return v + __int_as_float(t);
}
// sum across 64 lanes -> uniform scalar, VALU-only.
__device__ __forceinline__ float wave_sum(float v) {
    v = dpp_add<0x111, 0xF>(v);
    v = dpp_add<0x112, 0xF>(v);
    v = dpp_add<0x114, 0xF>(v);
    v = dpp_add<0x118, 0xF>(v);
    v = dpp_add<0x142, 0xA>(v);
    v = dpp_add<0x143, 0xC>(v);
    return rlane(v, 63);
}
// per-half (32-lane) sum, broadcast to that half's lanes
__device__ __forceinline__ float half_sum(float v, bool hf) {
    v = dpp_add<0x111, 0xF>(v);
    v = dpp_add<0x112, 0xF>(v);
    v = dpp_add<0x114, 0xF>(v);
    v = dpp_add<0x118, 0xF>(v);
    v = dpp_add<0x142, 0xA>(v);   // lane31/lane63 hold the two half sums
    const float lo = rlane(v, 31);
    const float hi = rlane(v, 63);
    return hf ? hi : lo;
}

#if __has_builtin(__builtin_amdgcn_exp2f)
#define EXP2F(x) __builtin_amdgcn_exp2f(x)
#else
#define EXP2F(x) exp2f(x)
#endif
#if __has_builtin(__builtin_amdgcn_logf)
#define LOG2F(x) __builtin_amdgcn_logf(x)
#else
#define LOG2F(x) __log2f(x)
#endif

// r9 = r8 structure with register starvation fixed:
//  - waves_per_eu(4,8): VGPR budget 128 (r8's waves_per_eu(8) forced VGPR=32 ->
//    coefficient/ring quads demoted to per-step LDS/scratch re-reads; all waves
//    stalled together -> 27% per-SIMD issue. r7-vs-r8 per-wave-step comparison
//    (105 vs 124 cy) plus FETCH/WRITE excess was the evidence.)
//  - setup runs on wave 7; the var pass (p=0) and all ring e2-fills are moved
//    BEFORE the table barrier (they need no tables) -> overlap with the u-chain.
//  - inner loop / warm-up scheme byte-identical to the r8-validated version.
__attribute__((amdgpu_flat_work_group_size(512, 512)))
__attribute__((amdgpu_waves_per_eu(4, 8)))
__global__ void garch_fused(
    const float* __restrict__ res,   // (B, S)
    const float* __restrict__ Wih,   // (64, 2)
    const float* __restrict__ bih,   // (64,)
    const float* __restrict__ Whh,   // (64, 64)
    const float* __restrict__ bhh,   // (64,)
    const float* __restrict__ fcw,   // (64,)
    const float* __restrict__ fcb,   // (1,)
    float* __restrict__ out)         // (B, S)
{
    __shared__ __align__(16) float Wl[4096];     // staged Whh (setup only)
    __shared__ __align__(16) float tabA[1024];   // quad-major K*alpha circulant
    __shared__ __align__(16) float tabB[1024];   // quad-major TRUE-beta circulant
    __shared__ __align__(16) float ring[1024];   // 8 waves x 2 halves x 64 e2 ring
    __shared__ __align__(16) float ubuf[64];
    __shared__ float alpS[32], betS[32], gpreS[32], scS[4];

    const int tid  = threadIdx.x;
    const int lane = tid & 63;
    const int wv   = tid >> 6;
    const int l    = lane & 31;
    const bool hf  = (lane >= 32);

    const float Kc  = 1.44269504088896340736f;
    const float LN2 = 0.69314718055994530942f;

    // ---- cooperative stage Whh -> LDS ----
    {
        const f32x4* w4 = (const f32x4*)Whh;
        f32x4* wl4 = (f32x4*)Wl;
        for (int i = tid; i < 1024; i += 512) wl4[i] = w4[i];
    }
    __syncthreads();

    const int rp = blockIdx.x;               // row pair
    const int p  = wv;                       // segment 0..7
    const float* __restrict__ row  = res + (size_t)(2 * rp + (hf ? 1 : 0)) * S_LEN;
    float* __restrict__       orow = out + (size_t)(2 * rp + (hf ? 1 : 0)) * S_LEN;

    float* __restrict__ ringw = &ring[wv * 128 + (hf ? 64 : 0)];
    const int rotaddr = ((lane & 32) | ((l + 31) & 31)) << 2;

    // ======== pre-barrier prologue (no tables needed) ========
    float varh = 0.f, sigK = 0.f, carry = 0.f, ldn, eN_hold;
    int c0w, warm;

    if (p == 0) {
        // sigma0 = var(row, ddof=1), per half — overlaps wave 7's u-chain
        float s1 = 0.f, s2 = 0.f;
#pragma unroll 8
        for (int i = 0; i < 64; ++i) {
            const float x = row[i * 32 + l];
            s1 += x;
            s2 = fmaf(x, x, s2);
        }
        s1 = half_sum(s1, hf);
        s2 = half_sum(s2, hf);
        const float mean = s1 * (1.0f / S_LEN);
        varh = (s2 - s1 * mean) * (1.0f / (S_LEN - 1));
        sigK = Kc * varh;
        carry = sigK;

        const float e0 = row[l], e1 = row[32 + l];
        ringw[l] = e0 * e0;          // slot0 = e2(0)
        ringw[32 + l] = 0.f;         // e2(-1) = 0 boundary for FIR(0)
        eN_hold = e1 * e1;           // slot1 written post-barrier (after FIR)
        ldn = row[64 + l];           // raw chunk 2
        c0w = 0; warm = 0;
    } else {
        const int cw0 = 8 * p - 1;   // warm-up chunk (odd)
        const float eP = row[(cw0 - 1) * 32 + l];
        const float eC = row[cw0 * 32 + l];
        const float eN = row[(cw0 + 1) * 32 + l];
        ringw[((cw0 - 1) & 1) * 32 + l] = eP * eP;
        ringw[(cw0 & 1) * 32 + l]       = eC * eC;
        eN_hold = eN * eN;           // written post-barrier, after warm-init reads
        ldn = row[(cw0 + 2) * 32 + l];
        c0w = cw0; warm = 1;
    }
    asm volatile("" ::: "memory");

    // ---- wave 7: u-chain + table build (LDS-sourced matvec) ----
    if (wv == 7) {
        const float w0l = Wih[lane * 2], w1l = Wih[lane * 2 + 1];
        const float blp = bih[lane] + bhh[lane];
        const float fl  = fcw[lane];

        const float A0  = Kc * wave_sum(fl * w0l);
        const float b0t = wave_sum(fl * w1l);
        const float Cg  = Kc * (wave_sum(fl * blp) + fcb[0]);
        if (lane == 0) { alpS[0] = A0; betS[0] = b0t; }
        float gpre_ = Cg, ginf_ = Cg;

        ubuf[lane] = fl;
        asm volatile("" ::: "memory");
        const f32x4* uq4 = (const f32x4*)ubuf;
        float u;
        {
            float n0 = 0.f, n1 = 0.f, n2 = 0.f, n3 = 0.f;
#pragma unroll 4
            for (int q = 0; q < 16; ++q) {
                const f32x4 uq = uq4[q];
                n0 = fmaf(Wl[(4 * q + 0) * 64 + lane], uq.x, n0);
                n1 = fmaf(Wl[(4 * q + 1) * 64 + lane], uq.y, n1);
                n2 = fmaf(Wl[(4 * q + 2) * 64 + lane], uq.z, n2);
                n3 = fmaf(Wl[(4 * q + 3) * 64 + lane], uq.w, n3);
            }
            u = (n0 + n1) + (n2 + n3);
        }
#pragma unroll 1
        for (int i = 1; i < 48; ++i) {
            const float daK = Kc * wave_sum(u * w0l);
            const float dbT = wave_sum(u * w1l);        // TRUE beta_i
            const float dgK = Kc * wave_sum(u * blp);   // K*g_{i-1}
            if (lane == 0 && i < 32) { alpS[i] = daK; betS[i] = dbT; }
            gpre_ += (lane >= i) ? dgK : 0.f;
            ginf_ += dgK;
            ubuf[lane] = u;
            asm volatile("" ::: "memory");
            float n0 = 0.f, n1 = 0.f, n2 = 0.f, n3 = 0.f;
#pragma unroll 4
            for (int q = 0; q < 16; ++q) {
                const f32x4 uq = uq4[q];
                n0 = fmaf(Wl[(4 * q + 0) * 64 + lane], uq.x, n0);
                n1 = fmaf(Wl[(4 * q + 1) * 64 + lane], uq.y, n1);
                n2 = fmaf(Wl[(4 * q + 2) * 64 + lane], uq.z, n2);
                n3 = fmaf(Wl[(4 * q + 3) * 64 + lane], uq.w, n3);
            }
            u = (n0 + n1) + (n2 + n3);
        }
        asm volatile("" ::: "memory");
        // quad-major tables: tab[(q*32 + l)*4 + w] = T[l][4q+w], lags<4 zeroed
        for (int f = lane; f < 1024; f += 64) {
            const int lr = f >> 5, jc = f & 31;
            const int m = (lr - jc) & 31;
            const int dst = (((jc >> 2) * 32 + lr) << 2) + (jc & 3);
            tabA[dst] = (m < 4) ? 0.f : alpS[m];
            tabB[dst] = (m < 4) ? 0.f : betS[m];
        }
        if (lane < 32) gpreS[lane] = gpre_;
        if (lane == 0) scS[0] = ginf_;
    }
    __syncthreads();

    // ======== post-barrier: table-dependent init ========
    const float ginf = scS[0];
    const float bb0 = betS[0], bb1 = betS[1], bb2 = betS[2], bb3 = betS[3];
    const float Ka0 = alpS[0], Ka1 = alpS[1], Ka2 = alpS[2], Ka3 = alpS[3];

#define FIR4(DST, SB) { \
    const int a0_ = ((SB) << 5) + l; \
    const float x0_ = ringw[a0_]; \
    const float x1_ = ringw[(a0_ - 1) & 63]; \
    const float x2_ = ringw[(a0_ - 2) & 63]; \
    const float x3_ = ringw[(a0_ - 3) & 63]; \
    (DST) = fmaf(Ka3, x3_, fmaf(Ka2, x2_, fmaf(Ka1, x1_, Ka0 * x0_))); }

#define BCASTI(DST, V, IDX) { \
    const float lo_ = rlane((V), (IDX)); \
    const float hi_ = rlane((V), 32 + (IDX)); \
    (DST) = hf ? hi_ : lo_; }

    const f32x4* tA4 = (const f32x4*)tabA;
    const f32x4* tB4 = (const f32x4*)tabB;

    float acc, p1, p2, p3, vout = 0.f;

    if (p == 0) {
        float e4C;
        FIR4(e4C, 0);
        acc = gpreS[l] + e4C;        // K*Gamma_{l+1} + FIR lags 0..3 of chunk 0
        BCASTI(p1, acc, 0); BCASTI(p2, acc, 1); BCASTI(p3, acc, 2);
        ringw[32 + l] = eN_hold;     // slot1 = e2(1)
        asm volatile("" ::: "memory");
    } else {
        const int cw0 = 8 * p - 1;
        float e4C;
        FIR4(e4C, cw0 & 1);          // FIR(cw0); boundary from e2(cw0-1)
        acc = ginf + e4C;
        // exact alpha wrap-init from chunk cw0-1 (lags l+1..31)
        const f32x4* pq = (const f32x4*)(ringw + ((cw0 - 1) & 1) * 32);
#pragma unroll
        for (int q = 0; q < 8; ++q) {
            const f32x4 aqv = tA4[q * 32 + l];
            const f32x4 eq = pq[q];
#pragma unroll
            for (int w = 0; w < 4; ++w) {
                const int j = 4 * q + w;
                const float cf = (j > l) ? aqv[w] : 0.f;
                acc = fmaf(cf, eq[w], acc);
            }
        }
        BCASTI(p1, acc, 0); BCASTI(p2, acc, 1); BCASTI(p3, acc, 2);
        sigK = 0.f; carry = 0.f;     // zero sigma-history: decays over 32 warm steps
        ringw[((cw0 + 1) & 1) * 32 + l] = eN_hold;   // e2(cw0+1), after init reads
        asm volatile("" ::: "memory");
    }

    const int ncc = 8 + warm;
    const bool p0 = (p == 0);

#pragma unroll 1
    for (int cc = 0; cc < ncc; ++cc) {
        const int c = c0w + cc;
        const int s = c & 1;
        float e4N;
        FIR4(e4N, s ^ 1);                    // FIR(chunk c+1)
        const float ginfE = ginf + e4N;      // reset value carries FIR(c+1)
        const float sigchunk = carry;
        const f32x4* ringq = (const f32x4*)(ringw + (s << 5));

#pragma unroll
        for (int jg = 0; jg < 4; ++jg) {
            const f32x4 caq0 = tA4[(2 * jg) * 32 + l];
            const f32x4 caq1 = tA4[(2 * jg + 1) * 32 + l];
            const f32x4 cbq0 = tB4[(2 * jg) * 32 + l];
            const f32x4 cbq1 = tB4[(2 * jg + 1) * 32 + l];
            const f32x4 curA = ringq[jg * 2];
            const f32x4 curB = ringq[jg * 2 + 1];
#pragma unroll
            for (int k = 0; k < 8; ++k) {
                const int jj = (jg << 3) + k;
                const float ash = (k < 4) ? caq0[k] : caq1[k - 4];
                const float bsh = (k < 4) ? cbq0[k] : cbq1[k - 4];
                const float e2j = (k < 4) ? curA[k] : curB[k - 4];
                const float xp = fmaf(bb0, sigK, p1);     // on-chain
                acc = fmaf(bsh, sigK, acc);               // sigma lags >=4
                acc = fmaf(ash, e2j, acc);                // e2 lags >=4
                const bool mine = (l == jj);
                acc = mine ? ginfE : acc;                 // reset (incl. FIR(c+1))
                const float tlo = rlane(acc, (jj + 3) & 31);
                const float thi = rlane(acc, 32 + ((jj + 3) & 31));
                const float t = hf ? thi : tlo;           // hoisted-3 read, per half
                p1 = fmaf(bb1, sigK, p2);
                p2 = fmaf(bb2, sigK, p3);
                p3 = fmaf(bb3, sigK, t);
                const float ee = EXP2F(-__builtin_fabsf(xp));
                sigK = fmaxf(xp, 0.f) + LOG2F(1.0f + ee); // log2-domain softplus
                vout = mine ? sigK : vout;                // lane jj: sigma_{32c+jj+1}
            }
        }

        if (cc >= warm) {
            const float rotv = __int_as_float(
                __builtin_amdgcn_ds_bpermute(rotaddr, __float_as_int(vout)));
            const float sv = (l == 0) ? sigchunk : rotv;
            float outv = fmaf(sv, LN2, 1e-6f);
            if (p0 && cc == 0) outv = (l == 0) ? varh : outv;   // t=0: exact variance
            orow[(c << 5) + l] = outv;
        }
        {
            const float c1v = rlane(vout, 31);
            const float c2v = rlane(vout, 63);
            carry = hf ? c2v : c1v;
        }
        ringw[(s << 5) + l] = ldn * ldn;     // slot s <- e2(c+2)
        const int nc3 = (c + 3 < 63) ? (c + 3) : 63;
        ldn = row[nc3 * 32 + l];
        asm volatile("" ::: "memory");
    }
#undef FIR4
#undef BCASTI
}

extern "C" void kernel_launch(void* const* d_in, const int* in_sizes, int n_in,
                              void* d_out, int out_size, void* d_ws, size_t ws_size,
                              hipStream_t stream) {
    const float* res = (const float*)d_in[0];
    const float* Wih = (const float*)d_in[1];
    const float* bih = (const float*)d_in[2];
    const float* Whh = (const float*)d_in[3];
    const float* bhh = (const float*)d_in[4];
    const float* fcw = (const float*)d_in[5];
    const float* fcb = (const float*)d_in[6];
    float* out = (float*)d_out;

    hipLaunchKernelGGL(garch_fused, dim3(1024), dim3(512), 0, stream,
                       res, Wih, bih, Whh, bhh, fcw, fcb, out);
}

// Round 10
// 189.580 us; speedup vs baseline: 1.1274x; 1.1274x over previous
//
#include <hip/hip_runtime.h>

#define S_LEN 2048

typedef float f32x4 __attribute__((ext_vector_type(4)));

__device__ __forceinline__ float rlane(float v, int l) {
    return __int_as_float(__builtin_amdgcn_readlane(__float_as_int(v), l));
}

template<int CTRL, int RM>
__device__ __forceinline__ float dpp_add(float v) {
    int t = __builtin_amdgcn_update_dpp(0, __float_as_int(v), CTRL, RM, 0xF, true);
    return v + __int_as_float(t);
}
// sum across 64 lanes -> uniform scalar, VALU-only.
__device__ __forceinline__ float wave_sum(float v) {
    v = dpp_add<0x111, 0xF>(v);
    v = dpp_add<0x112, 0xF>(v);
    v = dpp_add<0x114, 0xF>(v);
    v = dpp_add<0x118, 0xF>(v);
    v = dpp_add<0x142, 0xA>(v);
    v = dpp_add<0x143, 0xC>(v);
    return rlane(v, 63);
}
// per-half (32-lane) sum, broadcast to that half's lanes
__device__ __forceinline__ float half_sum(float v, bool hf) {
    v = dpp_add<0x111, 0xF>(v);
    v = dpp_add<0x112, 0xF>(v);
    v = dpp_add<0x114, 0xF>(v);
    v = dpp_add<0x118, 0xF>(v);
    v = dpp_add<0x142, 0xA>(v);   // lane31/lane63 hold the two half sums
    const float lo = rlane(v, 31);
    const float hi = rlane(v, 63);
    return hf ? hi : lo;
}

#if __has_builtin(__builtin_amdgcn_exp2f)
#define EXP2F(x) __builtin_amdgcn_exp2f(x)
#else
#define EXP2F(x) exp2f(x)
#endif
#if __has_builtin(__builtin_amdgcn_logf)
#define LOG2F(x) __builtin_amdgcn_logf(x)
#else
#define LOG2F(x) __log2f(x)
#endif

// r10 = fused launch (r8/r9 overhead win) + r7 codegen (pinned coefficient regs,
// measured 105 cy/wave-step vs 134/158 when the allocator demotes to 32-36 VGPRs).
//  - 256-thread blocks: 4 waves = 4 segments x (16 chunks + 1 warm chunk of 32 steps).
//    4096 waves, VGPR ~100 -> 4 waves/SIMD -> ALL waves resident, single pass.
//  - u-chain on wave 3, overlapped with wave 0's variance pass (pre-barrier
//    prologue, r9-validated); coefficients loaded once per lane from LDS alpS/betS
//    into 64 asm-PINNED registers (the only mechanism that has beaten the
//    allocator's occupancy heuristic this session).
//  - inner loop / warm-up / FIR-in-reset machinery byte-identical to the
//    r8/r9-validated warm=1 form.
__attribute__((amdgpu_flat_work_group_size(256, 256)))
__attribute__((amdgpu_waves_per_eu(4, 8)))
__global__ void garch_fused(
    const float* __restrict__ res,   // (B, S)
    const float* __restrict__ Wih,   // (64, 2)
    const float* __restrict__ bih,   // (64,)
    const float* __restrict__ Whh,   // (64, 64)
    const float* __restrict__ bhh,   // (64,)
    const float* __restrict__ fcw,   // (64,)
    const float* __restrict__ fcb,   // (1,)
    float* __restrict__ out)         // (B, S)
{
    __shared__ __align__(16) float Wl[4096];     // staged Whh (setup only)
    __shared__ __align__(16) float ring[512];    // 4 waves x 2 halves x 64 e2 ring
    __shared__ __align__(16) float ubuf[64];
    __shared__ float alpS[32], betS[32], gpreS[32], scS[4];

    const int tid  = threadIdx.x;
    const int lane = tid & 63;
    const int wv   = tid >> 6;
    const int l    = lane & 31;
    const bool hf  = (lane >= 32);

    const float Kc  = 1.44269504088896340736f;
    const float LN2 = 0.69314718055994530942f;

    // ---- cooperative stage Whh -> LDS ----
    {
        const f32x4* w4 = (const f32x4*)Whh;
        f32x4* wl4 = (f32x4*)Wl;
        for (int i = tid; i < 1024; i += 256) wl4[i] = w4[i];
    }
    __syncthreads();

    const int rp = blockIdx.x;               // row pair
    const int p  = wv;                       // segment 0..3 (16 chunks each)
    const float* __restrict__ row  = res + (size_t)(2 * rp + (hf ? 1 : 0)) * S_LEN;
    float* __restrict__       orow = out + (size_t)(2 * rp + (hf ? 1 : 0)) * S_LEN;

    float* __restrict__ ringw = &ring[wv * 128 + (hf ? 64 : 0)];
    const int rotaddr = ((lane & 32) | ((l + 31) & 31)) << 2;

    // ======== pre-barrier prologue (no tables needed) ========
    float varh = 0.f, sigK = 0.f, carry = 0.f, ldn, eN_hold;
    int c0w, warm;

    if (p == 0) {
        // sigma0 = var(row, ddof=1), per half — overlaps wave 3's u-chain
        float s1 = 0.f, s2 = 0.f;
#pragma unroll 8
        for (int i = 0; i < 64; ++i) {
            const float x = row[i * 32 + l];
            s1 += x;
            s2 = fmaf(x, x, s2);
        }
        s1 = half_sum(s1, hf);
        s2 = half_sum(s2, hf);
        const float mean = s1 * (1.0f / S_LEN);
        varh = (s2 - s1 * mean) * (1.0f / (S_LEN - 1));
        sigK = Kc * varh;
        carry = sigK;

        const float e0 = row[l], e1 = row[32 + l];
        ringw[l] = e0 * e0;          // slot0 = e2(0)
        ringw[32 + l] = 0.f;         // e2(-1) = 0 boundary for FIR(0)
        eN_hold = e1 * e1;           // slot1 written post-barrier (after FIR)
        ldn = row[64 + l];           // raw chunk 2
        c0w = 0; warm = 0;
    } else {
        const int cw0 = 16 * p - 1;  // warm-up chunk (odd)
        const float eP = row[(cw0 - 1) * 32 + l];
        const float eC = row[cw0 * 32 + l];
        const float eN = row[(cw0 + 1) * 32 + l];
        ringw[((cw0 - 1) & 1) * 32 + l] = eP * eP;
        ringw[(cw0 & 1) * 32 + l]       = eC * eC;
        eN_hold = eN * eN;           // written post-barrier, after warm-init reads
        ldn = row[(cw0 + 2) * 32 + l];
        c0w = cw0; warm = 1;
    }
    asm volatile("" ::: "memory");

    // ---- wave 3: u-chain + coefficient publish (LDS-sourced matvec) ----
    if (wv == 3) {
        const float w0l = Wih[lane * 2], w1l = Wih[lane * 2 + 1];
        const float blp = bih[lane] + bhh[lane];
        const float fl  = fcw[lane];

        const float A0  = Kc * wave_sum(fl * w0l);
        const float b0t = wave_sum(fl * w1l);
        const float Cg  = Kc * (wave_sum(fl * blp) + fcb[0]);
        if (lane == 0) { alpS[0] = A0; betS[0] = b0t; }
        float gpre_ = Cg, ginf_ = Cg;

        ubuf[lane] = fl;
        asm volatile("" ::: "memory");
        const f32x4* uq4 = (const f32x4*)ubuf;
        float u;
        {
            float n0 = 0.f, n1 = 0.f, n2 = 0.f, n3 = 0.f;
#pragma unroll 4
            for (int q = 0; q < 16; ++q) {
                const f32x4 uq = uq4[q];
                n0 = fmaf(Wl[(4 * q + 0) * 64 + lane], uq.x, n0);
                n1 = fmaf(Wl[(4 * q + 1) * 64 + lane], uq.y, n1);
                n2 = fmaf(Wl[(4 * q + 2) * 64 + lane], uq.z, n2);
                n3 = fmaf(Wl[(4 * q + 3) * 64 + lane], uq.w, n3);
            }
            u = (n0 + n1) + (n2 + n3);
        }
#pragma unroll 1
        for (int i = 1; i < 48; ++i) {
            const float daK = Kc * wave_sum(u * w0l);
            const float dbT = wave_sum(u * w1l);        // TRUE beta_i
            const float dgK = Kc * wave_sum(u * blp);   // K*g_{i-1}
            if (lane == 0 && i < 32) { alpS[i] = daK; betS[i] = dbT; }
            gpre_ += (lane >= i) ? dgK : 0.f;
            ginf_ += dgK;
            ubuf[lane] = u;
            asm volatile("" ::: "memory");
            float n0 = 0.f, n1 = 0.f, n2 = 0.f, n3 = 0.f;
#pragma unroll 4
            for (int q = 0; q < 16; ++q) {
                const f32x4 uq = uq4[q];
                n0 = fmaf(Wl[(4 * q + 0) * 64 + lane], uq.x, n0);
                n1 = fmaf(Wl[(4 * q + 1) * 64 + lane], uq.y, n1);
                n2 = fmaf(Wl[(4 * q + 2) * 64 + lane], uq.z, n2);
                n3 = fmaf(Wl[(4 * q + 3) * 64 + lane], uq.w, n3);
            }
            u = (n0 + n1) + (n2 + n3);
        }
        asm volatile("" ::: "memory");
        if (lane < 32) gpreS[lane] = gpre_;
        if (lane == 0) scS[0] = ginf_;
    }
    __syncthreads();

    // ======== post-barrier: coefficient registers (PINNED) + init ========
    const float ginf = scS[0];
    const float bb0 = betS[0], bb1 = betS[1], bb2 = betS[2], bb3 = betS[3];
    const float Ka0 = alpS[0], Ka1 = alpS[1], Ka2 = alpS[2], Ka3 = alpS[3];

    // circulant rows into registers: ca[q][w] = K*alpha'_{(l-4q-w)&31}, cb = beta'
    f32x4 ca[8], cb[8];
#pragma unroll
    for (int q = 0; q < 8; ++q) {
#pragma unroll
        for (int w = 0; w < 4; ++w) {
            const int m = (l - (4 * q + w)) & 31;
            const bool z = (m < 4);
            ca[q][w] = z ? 0.f : alpS[m];
            cb[q][w] = z ? 0.f : betS[m];
        }
    }
    asm("" : "+v"(ca[0]), "+v"(ca[1]), "+v"(ca[2]), "+v"(ca[3]),
             "+v"(ca[4]), "+v"(ca[5]), "+v"(ca[6]), "+v"(ca[7]),
             "+v"(cb[0]), "+v"(cb[1]), "+v"(cb[2]), "+v"(cb[3]),
             "+v"(cb[4]), "+v"(cb[5]), "+v"(cb[6]), "+v"(cb[7]));

#define FIR4(DST, SB) { \
    const int a0_ = ((SB) << 5) + l; \
    const float x0_ = ringw[a0_]; \
    const float x1_ = ringw[(a0_ - 1) & 63]; \
    const float x2_ = ringw[(a0_ - 2) & 63]; \
    const float x3_ = ringw[(a0_ - 3) & 63]; \
    (DST) = fmaf(Ka3, x3_, fmaf(Ka2, x2_, fmaf(Ka1, x1_, Ka0 * x0_))); }

#define BCASTI(DST, V, IDX) { \
    const float lo_ = rlane((V), (IDX)); \
    const float hi_ = rlane((V), 32 + (IDX)); \
    (DST) = hf ? hi_ : lo_; }

    float acc, p1, p2, p3, vout = 0.f;

    if (p == 0) {
        float e4C;
        FIR4(e4C, 0);
        acc = gpreS[l] + e4C;        // K*Gamma_{l+1} + FIR lags 0..3 of chunk 0
        BCASTI(p1, acc, 0); BCASTI(p2, acc, 1); BCASTI(p3, acc, 2);
        ringw[32 + l] = eN_hold;     // slot1 = e2(1)
        asm volatile("" ::: "memory");
    } else {
        const int cw0 = 16 * p - 1;
        float e4C;
        FIR4(e4C, cw0 & 1);          // FIR(cw0); boundary from e2(cw0-1)
        acc = ginf + e4C;
        // exact alpha wrap-init from chunk cw0-1 (lags l+1..31)
        const f32x4* pq = (const f32x4*)(ringw + ((cw0 - 1) & 1) * 32);
#pragma unroll
        for (int q = 0; q < 8; ++q) {
            const f32x4 eq = pq[q];
#pragma unroll
            for (int w = 0; w < 4; ++w) {
                const int j = 4 * q + w;
                const float cf = (j > l) ? ca[q][w] : 0.f;
                acc = fmaf(cf, eq[w], acc);
            }
        }
        BCASTI(p1, acc, 0); BCASTI(p2, acc, 1); BCASTI(p3, acc, 2);
        sigK = 0.f; carry = 0.f;     // zero sigma-history: decays over 32 warm steps
        ringw[((cw0 + 1) & 1) * 32 + l] = eN_hold;   // e2(cw0+1), after init reads
        asm volatile("" ::: "memory");
    }

    const int ncc = 16 + warm;
    const bool p0 = (p == 0);

#pragma unroll 1
    for (int cc = 0; cc < ncc; ++cc) {
        const int c = c0w + cc;
        const int s = c & 1;
        float e4N;
        FIR4(e4N, s ^ 1);                    // FIR(chunk c+1)
        const float ginfE = ginf + e4N;      // reset value carries FIR(c+1)
        const float sigchunk = carry;
        const f32x4* ringq = (const f32x4*)(ringw + (s << 5));

#pragma unroll
        for (int jg = 0; jg < 4; ++jg) {
            const f32x4 curA = ringq[jg * 2];
            const f32x4 curB = ringq[jg * 2 + 1];
#pragma unroll
            for (int k = 0; k < 8; ++k) {
                const int jj = (jg << 3) + k;
                const float ash = ca[jj >> 2][jj & 3];    // pinned reg
                const float bsh = cb[jj >> 2][jj & 3];    // pinned reg
                const float e2j = (k < 4) ? curA[k] : curB[k - 4];
                const float xp = fmaf(bb0, sigK, p1);     // on-chain
                acc = fmaf(bsh, sigK, acc);               // sigma lags >=4
                acc = fmaf(ash, e2j, acc);                // e2 lags >=4
                const bool mine = (l == jj);
                acc = mine ? ginfE : acc;                 // reset (incl. FIR(c+1))
                const float tlo = rlane(acc, (jj + 3) & 31);
                const float thi = rlane(acc, 32 + ((jj + 3) & 31));
                const float t = hf ? thi : tlo;           // hoisted-3 read, per half
                p1 = fmaf(bb1, sigK, p2);
                p2 = fmaf(bb2, sigK, p3);
                p3 = fmaf(bb3, sigK, t);
                const float ee = EXP2F(-__builtin_fabsf(xp));
                sigK = fmaxf(xp, 0.f) + LOG2F(1.0f + ee); // log2-domain softplus
                vout = mine ? sigK : vout;                // lane jj: sigma_{32c+jj+1}
            }
        }

        if (cc >= warm) {
            const float rotv = __int_as_float(
                __builtin_amdgcn_ds_bpermute(rotaddr, __float_as_int(vout)));
            const float sv = (l == 0) ? sigchunk : rotv;
            float outv = fmaf(sv, LN2, 1e-6f);
            if (p0 && cc == 0) outv = (l == 0) ? varh : outv;   // t=0: exact variance
            orow[(c << 5) + l] = outv;
        }
        {
            const float c1v = rlane(vout, 31);
            const float c2v = rlane(vout, 63);
            carry = hf ? c2v : c1v;
        }
        ringw[(s << 5) + l] = ldn * ldn;     // slot s <- e2(c+2)
        const int nc3 = (c + 3 < 63) ? (c + 3) : 63;
        ldn = row[nc3 * 32 + l];
        asm volatile("" ::: "memory");
    }
#undef FIR4
#undef BCASTI
}

extern "C" void kernel_launch(void* const* d_in, const int* in_sizes, int n_in,
                              void* d_out, int out_size, void* d_ws, size_t ws_size,
                              hipStream_t stream) {
    const float* res = (const float*)d_in[0];
    const float* Wih = (const float*)d_in[1];
    const float* bih = (const float*)d_in[2];
    const float* Whh = (const float*)d_in[3];
    const float* bhh = (const float*)d_in[4];
    const float* fcw = (const float*)d_in[5];
    const float* fcb = (const float*)d_in[6];
    float* out = (float*)d_out;

    hipLaunchKernelGGL(garch_fused, dim3(1024), dim3(256), 0, stream,
                       res, Wih, bih, Whh, bhh, fcw, fcb, out);
}